// Round 5
// baseline (418.269 us; speedup 1.0000x reference)
//
#include <hip/hip_runtime.h>

// GINConv pipeline. R5: both GEMMs moved from fp32 VALU (32 TF, VALUBusy 29%,
// MfmaUtil 0) to bf16 hi/lo-split MFMA (3x mfma_f32_16x16x32_bf16 per product
// term; lo*lo dropped, ~1.5e-5 rel error). LDS planes XOR-swizzled (T2) since
// fragment reads are the stride-256B 16-way-conflict pattern.
//
//   CSR build (deg/scan/fill) -> gather-sum -> MFMA GEMM1 (+BN stats)
//   -> bnfinal -> MFMA GEMM2 (BN+ReLU fused in A-staging)
//
// NOTE: harness delivers integer inputs as int32 — edge_index is const int*.

#define N_NODES 50000
#define N_EDGES 800000
#define D_IN    128
#define D_HID   256
#define D_OUT   128
#define BN_EPS  1e-5f

#define NBLK_SCAN 49   // ceil(50000 / 1024)
#define GX_MLP    782  // ceil(50000 / 64)

typedef __attribute__((ext_vector_type(8))) __bf16 bf16x8;
typedef __attribute__((ext_vector_type(4))) float  f32x4;

__device__ __forceinline__ void split_bf16(float v, unsigned short& h, unsigned short& l)
{
    __bf16 bh = (__bf16)v;
    float  r  = v - (float)bh;
    __bf16 bl = (__bf16)r;
    h = __builtin_bit_cast(unsigned short, bh);
    l = __builtin_bit_cast(unsigned short, bl);
}

// ---------------- CSR build ----------------

__global__ __launch_bounds__(256) void deg_kernel(
    const int* __restrict__ ei, int* __restrict__ deg)
{
    const int e = blockIdx.x * 256 + threadIdx.x;
    if (e >= N_EDGES) return;
    atomicAdd(&deg[ei[N_EDGES + e]], 1);
}

__global__ __launch_bounds__(256) void scan1_kernel(
    const int* __restrict__ deg, int* __restrict__ bsum)
{
    __shared__ int ws[4];
    const int t = threadIdx.x;
    const int i0 = blockIdx.x * 1024 + t * 4;
    int s = 0;
    if (i0 + 3 < N_NODES) {
        const int4 d = *(const int4*)(deg + i0);
        s = d.x + d.y + d.z + d.w;
    } else {
        #pragma unroll
        for (int q = 0; q < 4; ++q) if (i0 + q < N_NODES) s += deg[i0 + q];
    }
    #pragma unroll
    for (int d = 32; d > 0; d >>= 1) s += __shfl_down(s, d);
    if ((t & 63) == 0) ws[t >> 6] = s;
    __syncthreads();
    if (t == 0) bsum[blockIdx.x] = ws[0] + ws[1] + ws[2] + ws[3];
}

__global__ __launch_bounds__(64) void scan2_kernel(
    int* __restrict__ bsum, int* __restrict__ off)
{
    const int lane = threadIdx.x;
    const int v = (lane < NBLK_SCAN) ? bsum[lane] : 0;
    int incl = v;
    #pragma unroll
    for (int d = 1; d < 64; d <<= 1) {
        const int up = __shfl_up(incl, d);
        if (lane >= d) incl += up;
    }
    if (lane < NBLK_SCAN) bsum[lane] = incl - v;
    if (lane == 0) off[N_NODES] = N_EDGES;
}

__global__ __launch_bounds__(256) void scan3_kernel(
    const int* __restrict__ deg, const int* __restrict__ bsum,
    int* __restrict__ off, int* __restrict__ cursor)
{
    __shared__ int ws[4];
    const int t = threadIdx.x;
    const int lane = t & 63, wid = t >> 6;
    const int i0 = blockIdx.x * 1024 + t * 4;
    int4 d = make_int4(0, 0, 0, 0);
    if (i0 + 3 < N_NODES) {
        d = *(const int4*)(deg + i0);
    } else {
        if (i0 + 0 < N_NODES) d.x = deg[i0 + 0];
        if (i0 + 1 < N_NODES) d.y = deg[i0 + 1];
        if (i0 + 2 < N_NODES) d.z = deg[i0 + 2];
    }
    const int tsum = d.x + d.y + d.z + d.w;
    int incl = tsum;
    #pragma unroll
    for (int dd = 1; dd < 64; dd <<= 1) {
        const int up = __shfl_up(incl, dd);
        if (lane >= dd) incl += up;
    }
    if (lane == 63) ws[wid] = incl;
    __syncthreads();
    int wbase = 0;
    for (int w = 0; w < wid; ++w) wbase += ws[w];
    const int e = bsum[blockIdx.x] + wbase + incl - tsum;
    int4 o;
    o.x = e; o.y = e + d.x; o.z = o.y + d.y; o.w = o.z + d.z;
    if (i0 + 3 < N_NODES) {
        *(int4*)(off + i0)    = o;
        *(int4*)(cursor + i0) = o;
    } else {
        if (i0 + 0 < N_NODES) { off[i0 + 0] = o.x; cursor[i0 + 0] = o.x; }
        if (i0 + 1 < N_NODES) { off[i0 + 1] = o.y; cursor[i0 + 1] = o.y; }
        if (i0 + 2 < N_NODES) { off[i0 + 2] = o.z; cursor[i0 + 2] = o.z; }
    }
}

__global__ __launch_bounds__(256) void fill_kernel(
    const int* __restrict__ ei, int* __restrict__ cursor, int* __restrict__ esrc)
{
    const int e = blockIdx.x * 256 + threadIdx.x;
    if (e >= N_EDGES) return;
    const int pos = atomicAdd(&cursor[ei[N_EDGES + e]], 1);
    esrc[pos] = ei[e];
}

// ---------------- gather ----------------

__global__ __launch_bounds__(256) void gather_kernel(
    const float* __restrict__ x, const int* __restrict__ off,
    const int* __restrict__ esrc, float* __restrict__ agg)
{
    const int gtid = blockIdx.x * 256 + threadIdx.x;
    const int node = gtid >> 6;
    const int lane = gtid & 63;
    if (node >= N_NODES) return;
    const int e0 = off[node], e1 = off[node + 1];
    float2 acc = make_float2(0.f, 0.f);
    for (int e = e0; e < e1; e += 64) {
        const int n = min(64, e1 - e);
        const int myS = (lane < n) ? esrc[e + lane] : 0;
        for (int j = 0; j < n; ++j) {
            const int s = __shfl(myS, j);
            const float2 v = ((const float2*)(x + (size_t)s * D_IN))[lane];
            acc.x += v.x;
            acc.y += v.y;
        }
    }
    ((float2*)(agg + (size_t)node * D_IN))[lane] = acc;
}

// ---------------- MFMA MLP layers ----------------
// MODE 1: h1 = (x+agg) @ W1 + b1, fused per-col sum/sumsq  (K=128, N=256)
// MODE 2: out = relu(h1*aco + cco) @ W2 + b2               (K=256, N=128)
//
// 64x64 block tile, 4 waves in 2x2; wave = 32x32 = 2x2 mfma_f32_16x16x32_bf16.
// LDS planes [row][k] bf16 hi/lo, XOR-swizzled: idx ^= (row&7)<<3 (ushort
// units = byte<<4) so fragment ds_read_b128 (lanes at 256B stride) is 2-way.
// Fragment layouts (m89): A row=l&15,k=(l>>4)*8+j ; B col=l&15 (stored [n][k]);
// C/D col=l&15, row=(l>>4)*4+reg.

template<int MODE>
__global__ __launch_bounds__(256) void mlp_kernel(
    const float* __restrict__ A0, const float* __restrict__ A1,
    const float* __restrict__ W,  const float* __restrict__ bias,
    const float* __restrict__ aco, const float* __restrict__ cco,
    float* __restrict__ outp, float* __restrict__ ssum, float* __restrict__ ssq)
{
    constexpr int LDA = (MODE == 1) ? 128 : 256;   // A row stride
    constexpr int LDW = (MODE == 1) ? 256 : 128;   // W row stride
    constexpr int LDO = (MODE == 1) ? 256 : 128;   // out row stride
    constexpr int NCH = (MODE == 1) ? 1 : 2;       // K chunks of 128

    __shared__ __attribute__((aligned(16))) unsigned short Ah[64 * 128];
    __shared__ __attribute__((aligned(16))) unsigned short Al[64 * 128];
    __shared__ __attribute__((aligned(16))) unsigned short Bh[64 * 128];
    __shared__ __attribute__((aligned(16))) unsigned short Bl[64 * 128];

    const int tid  = threadIdx.x;
    const int lane = tid & 63;
    const int w    = tid >> 6;
    const int wr   = w >> 1, wc = w & 1;
    const int lr   = lane & 15, kg = lane >> 4;
    const int i0   = blockIdx.x * 64;
    const int jb   = blockIdx.y * 64;

    f32x4 acc[2][2] = {};

    for (int ch = 0; ch < NCH; ++ch) {
        if (ch) __syncthreads();
        const int gk0 = ch * 128;

        // ---- stage A tile (64 rows x 128 k) as bf16 hi/lo ----
        #pragma unroll
        for (int it = 0; it < 8; ++it) {
            const int f   = tid + it * 256;
            const int row = f >> 5;
            const int k   = (f & 31) * 4;
            float4 v = make_float4(0.f, 0.f, 0.f, 0.f);
            const int grow = i0 + row;
            if (grow < N_NODES) {
                if (MODE == 1) {
                    const float4 xv = *(const float4*)(A0 + (size_t)grow * LDA + k);
                    const float4 av = *(const float4*)(A1 + (size_t)grow * LDA + k);
                    v = make_float4(xv.x + av.x, xv.y + av.y, xv.z + av.z, xv.w + av.w);
                } else {
                    const float4 hv = *(const float4*)(A0 + (size_t)grow * LDA + gk0 + k);
                    const float4 a4 = *(const float4*)(aco + gk0 + k);
                    const float4 c4 = *(const float4*)(cco + gk0 + k);
                    v = make_float4(fmaxf(fmaf(hv.x, a4.x, c4.x), 0.f),
                                    fmaxf(fmaf(hv.y, a4.y, c4.y), 0.f),
                                    fmaxf(fmaf(hv.z, a4.z, c4.z), 0.f),
                                    fmaxf(fmaf(hv.w, a4.w, c4.w), 0.f));
                }
            }
            ushort4 hh, ll;
            split_bf16(v.x, hh.x, ll.x);
            split_bf16(v.y, hh.y, ll.y);
            split_bf16(v.z, hh.z, ll.z);
            split_bf16(v.w, hh.w, ll.w);
            const int idx = (row * 128 + k) ^ ((row & 7) << 3);
            *(ushort4*)&Ah[idx] = hh;
            *(ushort4*)&Al[idx] = ll;
        }
        // ---- stage B tile transposed: [n][k] from W[k][n], hi/lo ----
        #pragma unroll
        for (int it = 0; it < 2; ++it) {
            const int n4 = (tid & 15) * 4;
            const int k0 = (tid >> 4) * 4 + it * 64;
            float4 wv[4];
            #pragma unroll
            for (int q = 0; q < 4; ++q)
                wv[q] = *(const float4*)(W + (size_t)(gk0 + k0 + q) * LDW + jb + n4);
            const float cols[4][4] = {
                {wv[0].x, wv[1].x, wv[2].x, wv[3].x},
                {wv[0].y, wv[1].y, wv[2].y, wv[3].y},
                {wv[0].z, wv[1].z, wv[2].z, wv[3].z},
                {wv[0].w, wv[1].w, wv[2].w, wv[3].w}};
            #pragma unroll
            for (int c = 0; c < 4; ++c) {
                const int n = n4 + c;
                ushort4 hh, ll;
                split_bf16(cols[c][0], hh.x, ll.x);
                split_bf16(cols[c][1], hh.y, ll.y);
                split_bf16(cols[c][2], hh.z, ll.z);
                split_bf16(cols[c][3], hh.w, ll.w);
                const int idx = (n * 128 + k0) ^ ((n & 7) << 3);
                *(ushort4*)&Bh[idx] = hh;
                *(ushort4*)&Bl[idx] = ll;
            }
        }
        __syncthreads();

        // ---- K loop: 4 steps of 32 ----
        #pragma unroll
        for (int ks = 0; ks < 4; ++ks) {
            bf16x8 ah[2], alo[2], bh[2], blo[2];
            #pragma unroll
            for (int mi = 0; mi < 2; ++mi) {
                const int ar   = wr * 32 + mi * 16 + lr;
                const int aidx = (ar * 128 + ks * 32 + kg * 8) ^ ((ar & 7) << 3);
                ah[mi]  = *(const bf16x8*)&Ah[aidx];
                alo[mi] = *(const bf16x8*)&Al[aidx];
            }
            #pragma unroll
            for (int ni = 0; ni < 2; ++ni) {
                const int br   = wc * 32 + ni * 16 + lr;
                const int bidx = (br * 128 + ks * 32 + kg * 8) ^ ((br & 7) << 3);
                bh[ni]  = *(const bf16x8*)&Bh[bidx];
                blo[ni] = *(const bf16x8*)&Bl[bidx];
            }
            #pragma unroll
            for (int mi = 0; mi < 2; ++mi)
                #pragma unroll
                for (int ni = 0; ni < 2; ++ni) {
                    acc[mi][ni] = __builtin_amdgcn_mfma_f32_16x16x32_bf16(
                        ah[mi], bh[ni], acc[mi][ni], 0, 0, 0);
                    acc[mi][ni] = __builtin_amdgcn_mfma_f32_16x16x32_bf16(
                        ah[mi], blo[ni], acc[mi][ni], 0, 0, 0);
                    acc[mi][ni] = __builtin_amdgcn_mfma_f32_16x16x32_bf16(
                        alo[mi], bh[ni], acc[mi][ni], 0, 0, 0);
                }
        }
    }

    // ---- epilogue ----
    #pragma unroll
    for (int ni = 0; ni < 2; ++ni) {
        const int col = jb + wc * 32 + ni * 16 + lr;
        const float bv = bias[col];
        if (MODE == 1) {
            float s = 0.f, sq = 0.f;
            #pragma unroll
            for (int mi = 0; mi < 2; ++mi)
                #pragma unroll
                for (int r = 0; r < 4; ++r) {
                    const int row = i0 + wr * 32 + mi * 16 + kg * 4 + r;
                    if (row < N_NODES) {
                        const float hv = acc[mi][ni][r] + bv;
                        outp[(size_t)row * LDO + col] = hv;
                        s += hv; sq += hv * hv;
                    }
                }
            s  += __shfl_xor(s, 16);  s  += __shfl_xor(s, 32);
            sq += __shfl_xor(sq, 16); sq += __shfl_xor(sq, 32);
            if (kg == 0) {
                atomicAdd(&ssum[col], s);
                atomicAdd(&ssq[col], sq);
            }
        } else {
            #pragma unroll
            for (int mi = 0; mi < 2; ++mi)
                #pragma unroll
                for (int r = 0; r < 4; ++r) {
                    const int row = i0 + wr * 32 + mi * 16 + kg * 4 + r;
                    if (row < N_NODES)
                        outp[(size_t)row * LDO + col] = acc[mi][ni][r] + bv;
                }
        }
    }
}

__global__ __launch_bounds__(256) void bnfinal_kernel(
    const float* __restrict__ ssum, const float* __restrict__ ssq,
    const float* __restrict__ gamma, const float* __restrict__ beta,
    float* __restrict__ aco, float* __restrict__ cco)
{
    const int j = threadIdx.x;
    const float inv_n = 1.0f / (float)N_NODES;
    const float mean = ssum[j] * inv_n;
    const float var  = ssq[j] * inv_n - mean * mean;
    const float rstd = rsqrtf(var + BN_EPS);
    const float a = rstd * gamma[j];
    aco[j] = a;
    cco[j] = beta[j] - mean * a;
}

extern "C" void kernel_launch(void* const* d_in, const int* in_sizes, int n_in,
                              void* d_out, int out_size, void* d_ws, size_t ws_size,
                              hipStream_t stream)
{
    const float* x     = (const float*)d_in[0];
    const int*   ei    = (const int*)d_in[1];      // int32 per harness contract
    const float* W1    = (const float*)d_in[2];
    const float* b1    = (const float*)d_in[3];
    const float* gamma = (const float*)d_in[4];
    const float* beta  = (const float*)d_in[5];
    const float* W2    = (const float*)d_in[6];
    const float* b2    = (const float*)d_in[7];
    float* out = (float*)d_out;

    // workspace layout (floats/ints):
    // agg[N*128] | h1[N*256] | ssum[256] | ssq[256] | aco[256] | cco[256]
    // | deg[N] | off[N+1] | cursor[N] | esrc[E] | bsum[64]
    float* agg  = (float*)d_ws;
    float* h1   = agg + (size_t)N_NODES * D_IN;
    float* ssum = h1  + (size_t)N_NODES * D_HID;
    float* ssq  = ssum + D_HID;
    float* aco  = ssq  + D_HID;
    float* cco  = aco  + D_HID;
    int* deg    = (int*)(cco + D_HID);
    int* off    = deg + N_NODES;
    int* cursor = off + N_NODES + 1;
    int* esrc   = cursor + N_NODES;
    int* bsum   = esrc + N_EDGES;

    hipMemsetAsync(deg,  0, N_NODES * sizeof(int), stream);
    hipMemsetAsync(ssum, 0, 2 * D_HID * sizeof(float), stream);

    deg_kernel<<<(N_EDGES + 255) / 256, 256, 0, stream>>>(ei, deg);
    scan1_kernel<<<NBLK_SCAN, 256, 0, stream>>>(deg, bsum);
    scan2_kernel<<<1, 64, 0, stream>>>(bsum, off);
    scan3_kernel<<<NBLK_SCAN, 256, 0, stream>>>(deg, bsum, off, cursor);
    fill_kernel<<<(N_EDGES + 255) / 256, 256, 0, stream>>>(ei, cursor, esrc);
    gather_kernel<<<(N_NODES * 64 + 255) / 256, 256, 0, stream>>>(x, off, esrc, agg);

    mlp_kernel<1><<<dim3(GX_MLP, 4), 256, 0, stream>>>(
        x, agg, W1, b1, nullptr, nullptr, h1, ssum, ssq);

    bnfinal_kernel<<<1, D_HID, 0, stream>>>(ssum, ssq, gamma, beta, aco, cco);

    mlp_kernel<2><<<dim3(GX_MLP, 2), 256, 0, stream>>>(
        h1, nullptr, W2, b2, aco, cco, out, nullptr, nullptr);
}

// Round 7
// 416.331 us; speedup vs baseline: 1.0047x; 1.0047x over previous
//
#include <hip/hip_runtime.h>

// GINConv pipeline. R6/R7: R5's MFMA GEMM was latency-bound (MfmaUtil 3%,
// VALUBusy 11% — per-block split_bf16 staging + LDS + barriers at 2 blk/CU).
// Fix: pre-split fp32 -> bf16 hi/lo ONCE into interleaved planes
// [row][k/8][hi8|lo8]; GEMMs load MFMA fragments DIRECTLY from global
// (L2/L3-served), no LDS, no barriers.
//   - x+agg split fused into gather epilogue
//   - BN+ReLU+split = one in-place pass over h1
//   - W1/W2 transpose+split once (tiny)
// Numerics identical to R5 (triple-MFMA hi/lo, lo*lo dropped).
//
// NOTE: harness delivers integer inputs as int32 — edge_index is const int*.

#define N_NODES 50000
#define N_EDGES 800000
#define D_IN    128
#define D_HID   256
#define D_OUT   128
#define BN_EPS  1e-5f

#define NBLK_SCAN 49   // ceil(50000 / 1024)
#define GX_MLP    782  // ceil(50000 / 64)

typedef __attribute__((ext_vector_type(8))) __bf16 bf16x8;
typedef __attribute__((ext_vector_type(4))) float  f32x4;
typedef __attribute__((ext_vector_type(8))) unsigned short us8;

__device__ __forceinline__ void split_bf16(float v, unsigned short& h, unsigned short& l)
{
    __bf16 bh = (__bf16)v;
    float  r  = v - (float)bh;
    __bf16 bl = (__bf16)r;
    h = __builtin_bit_cast(unsigned short, bh);
    l = __builtin_bit_cast(unsigned short, bl);
}

// ---------------- CSR build ----------------

__global__ __launch_bounds__(256) void deg_kernel(
    const int* __restrict__ ei, int* __restrict__ deg)
{
    const int e = blockIdx.x * 256 + threadIdx.x;
    if (e >= N_EDGES) return;
    atomicAdd(&deg[ei[N_EDGES + e]], 1);
}

__global__ __launch_bounds__(256) void scan1_kernel(
    const int* __restrict__ deg, int* __restrict__ bsum)
{
    __shared__ int ws[4];
    const int t = threadIdx.x;
    const int i0 = blockIdx.x * 1024 + t * 4;
    int s = 0;
    if (i0 + 3 < N_NODES) {
        const int4 d = *(const int4*)(deg + i0);
        s = d.x + d.y + d.z + d.w;
    } else {
        #pragma unroll
        for (int q = 0; q < 4; ++q) if (i0 + q < N_NODES) s += deg[i0 + q];
    }
    #pragma unroll
    for (int d = 32; d > 0; d >>= 1) s += __shfl_down(s, d);
    if ((t & 63) == 0) ws[t >> 6] = s;
    __syncthreads();
    if (t == 0) bsum[blockIdx.x] = ws[0] + ws[1] + ws[2] + ws[3];
}

__global__ __launch_bounds__(64) void scan2_kernel(
    int* __restrict__ bsum, int* __restrict__ off)
{
    const int lane = threadIdx.x;
    const int v = (lane < NBLK_SCAN) ? bsum[lane] : 0;
    int incl = v;
    #pragma unroll
    for (int d = 1; d < 64; d <<= 1) {
        const int up = __shfl_up(incl, d);
        if (lane >= d) incl += up;
    }
    if (lane < NBLK_SCAN) bsum[lane] = incl - v;
    if (lane == 0) off[N_NODES] = N_EDGES;
}

__global__ __launch_bounds__(256) void scan3_kernel(
    const int* __restrict__ deg, const int* __restrict__ bsum,
    int* __restrict__ off, int* __restrict__ cursor)
{
    __shared__ int ws[4];
    const int t = threadIdx.x;
    const int lane = t & 63, wid = t >> 6;
    const int i0 = blockIdx.x * 1024 + t * 4;
    int4 d = make_int4(0, 0, 0, 0);
    if (i0 + 3 < N_NODES) {
        d = *(const int4*)(deg + i0);
    } else {
        if (i0 + 0 < N_NODES) d.x = deg[i0 + 0];
        if (i0 + 1 < N_NODES) d.y = deg[i0 + 1];
        if (i0 + 2 < N_NODES) d.z = deg[i0 + 2];
    }
    const int tsum = d.x + d.y + d.z + d.w;
    int incl = tsum;
    #pragma unroll
    for (int dd = 1; dd < 64; dd <<= 1) {
        const int up = __shfl_up(incl, dd);
        if (lane >= dd) incl += up;
    }
    if (lane == 63) ws[wid] = incl;
    __syncthreads();
    int wbase = 0;
    for (int w = 0; w < wid; ++w) wbase += ws[w];
    const int e = bsum[blockIdx.x] + wbase + incl - tsum;
    int4 o;
    o.x = e; o.y = e + d.x; o.z = o.y + d.y; o.w = o.z + d.z;
    if (i0 + 3 < N_NODES) {
        *(int4*)(off + i0)    = o;
        *(int4*)(cursor + i0) = o;
    } else {
        if (i0 + 0 < N_NODES) { off[i0 + 0] = o.x; cursor[i0 + 0] = o.x; }
        if (i0 + 1 < N_NODES) { off[i0 + 1] = o.y; cursor[i0 + 1] = o.y; }
        if (i0 + 2 < N_NODES) { off[i0 + 2] = o.z; cursor[i0 + 2] = o.z; }
    }
}

__global__ __launch_bounds__(256) void fill_kernel(
    const int* __restrict__ ei, int* __restrict__ cursor, int* __restrict__ esrc)
{
    const int e = blockIdx.x * 256 + threadIdx.x;
    if (e >= N_EDGES) return;
    const int pos = atomicAdd(&cursor[ei[N_EDGES + e]], 1);
    esrc[pos] = ei[e];
}

// ---------------- gather + self + bf16 split (fused) ----------------
// xp layout: [row][k/8][hi8|lo8] ushorts, row stride 256.

__global__ __launch_bounds__(256) void gather_kernel(
    const float* __restrict__ x, const int* __restrict__ off,
    const int* __restrict__ esrc, unsigned short* __restrict__ xp)
{
    const int gtid = blockIdx.x * 256 + threadIdx.x;
    const int node = gtid >> 6;
    const int lane = gtid & 63;
    if (node >= N_NODES) return;
    const int e0 = off[node], e1 = off[node + 1];
    const float2 xv = ((const float2*)(x + (size_t)node * D_IN))[lane];
    float2 acc = xv;                               // (1+eps)*x with eps=0
    for (int e = e0; e < e1; e += 64) {
        const int n = min(64, e1 - e);
        const int myS = (lane < n) ? esrc[e + lane] : 0;
        for (int j = 0; j < n; ++j) {
            const int s = __shfl(myS, j);
            const float2 v = ((const float2*)(x + (size_t)s * D_IN))[lane];
            acc.x += v.x;
            acc.y += v.y;
        }
    }
    unsigned short h0, l0, h1_, l1_;
    split_bf16(acc.x, h0, l0);
    split_bf16(acc.y, h1_, l1_);
    // channels 2*lane, 2*lane+1 -> block b = lane>>2, pos = (2*lane)&7
    const int o = node * 256 + (lane >> 2) * 16 + ((2 * lane) & 7);
    *(ushort2*)&xp[o]     = make_ushort2(h0, h1_);
    *(ushort2*)&xp[o + 8] = make_ushort2(l0, l1_);
}

// ---------------- W transpose + split ----------------
// src [K][N] f32 -> dst [n][k/8][hi8|lo8] ushorts (row stride 2K).

__global__ __launch_bounds__(256) void wsplit_kernel(
    const float* __restrict__ src, unsigned short* __restrict__ dst,
    int K, int N)
{
    __shared__ float tile[64][65];
    const int k0 = blockIdx.x * 64, n0 = blockIdx.y * 64;
    const int t = threadIdx.x;
    const int tr = t >> 4, tc4 = (t & 15) * 4;
    #pragma unroll
    for (int i = 0; i < 4; ++i) {
        const int r = tr + i * 16;
        *(float4*)&tile[r][tc4] = *(const float4*)(src + (size_t)(k0 + r) * N + n0 + tc4);
    }
    __syncthreads();
    #pragma unroll
    for (int i = 0; i < 4; ++i) {
        const int n = tr + i * 16;
        ushort4 hh, ll;
        split_bf16(tile[tc4 + 0][n], hh.x, ll.x);
        split_bf16(tile[tc4 + 1][n], hh.y, ll.y);
        split_bf16(tile[tc4 + 2][n], hh.z, ll.z);
        split_bf16(tile[tc4 + 3][n], hh.w, ll.w);
        const int kk = k0 + tc4;                 // multiple of 4
        const int o = (n0 + n) * 2 * K + ((kk >> 3) << 4) + (kk & 7);
        *(ushort4*)&dst[o]     = hh;
        *(ushort4*)&dst[o + 8] = ll;
    }
}

// ---------------- BN + ReLU + split, in place over h1 ----------------
// h1 fp32 [row][256] -> same bytes reused as [row][k/8][hi8|lo8] ushorts.
// Each thread reads and rewrites exactly its own 32-byte span (race-free).
// h1_in / a2_out alias intentionally; NOT __restrict__ so ordering is kept.

__global__ __launch_bounds__(256) void bnrelu_split_kernel(
    const float* h1_in, unsigned short* a2_out,
    const float* __restrict__ aco, const float* __restrict__ cco)
{
    const int t = blockIdx.x * 256 + threadIdx.x;
    if (t >= N_NODES * 32) return;
    const int row = t >> 5, cb = t & 31;         // block of 8 channels
    const float* p = h1_in + (size_t)row * 256 + cb * 8;
    const float4 v0 = *(const float4*)p;
    const float4 v1 = *(const float4*)(p + 4);
    const float4 a0 = *(const float4*)(aco + cb * 8);
    const float4 a1 = *(const float4*)(aco + cb * 8 + 4);
    const float4 c0 = *(const float4*)(cco + cb * 8);
    const float4 c1 = *(const float4*)(cco + cb * 8 + 4);
    float r[8];
    r[0] = fmaxf(fmaf(v0.x, a0.x, c0.x), 0.f);
    r[1] = fmaxf(fmaf(v0.y, a0.y, c0.y), 0.f);
    r[2] = fmaxf(fmaf(v0.z, a0.z, c0.z), 0.f);
    r[3] = fmaxf(fmaf(v0.w, a0.w, c0.w), 0.f);
    r[4] = fmaxf(fmaf(v1.x, a1.x, c1.x), 0.f);
    r[5] = fmaxf(fmaf(v1.y, a1.y, c1.y), 0.f);
    r[6] = fmaxf(fmaf(v1.z, a1.z, c1.z), 0.f);
    r[7] = fmaxf(fmaf(v1.w, a1.w, c1.w), 0.f);
    us8 hi, lo;
    #pragma unroll
    for (int q = 0; q < 8; ++q) {
        unsigned short h, l;
        split_bf16(r[q], h, l);
        hi[q] = h; lo[q] = l;
    }
    unsigned short* d = a2_out + (size_t)row * 512 + cb * 16;
    *(us8*)d       = hi;
    *(us8*)(d + 8) = lo;
}

// ---------------- MFMA GEMMs, fragments direct from global ----------------
// MODE 1: h1 = (x+agg) @ W1 + b1 (+ BN col stats)   A=xp  B=w1t  K=128 N=256
// MODE 2: out = a2 @ W2 + b2                        A=a2p B=w2t  K=256 N=128
// Block: 4 waves 2x2, tile 64x64; wave 32x32 = 2x2 mfma_f32_16x16x32_bf16.
// Plane layout [row][k/8][hi8|lo8]: frag (row, k=ks*32+kg*8) at
// ushort offset row*2K + ks*64 + kg*16 (+8 for lo). Triple MFMA, lo*lo dropped.
// OOB A-rows (50000..50047) read garbage inside d_ws; MFMA row-independence
// keeps garbage confined to C-rows that the store masks out.

template<int MODE>
__global__ __launch_bounds__(256) void mlp_kernel(
    const unsigned short* __restrict__ Ap, const unsigned short* __restrict__ Bp,
    const float* __restrict__ bias, float* __restrict__ outp,
    float* __restrict__ ssum, float* __restrict__ ssq)
{
    constexpr int K   = (MODE == 1) ? 128 : 256;
    constexpr int NV  = (MODE == 1) ? 256 : 128;
    constexpr int LDP = 2 * K;
    const int tid = threadIdx.x;
    const int lane = tid & 63;
    const int w  = tid >> 6;
    const int wr = w >> 1, wc = w & 1;
    const int lr = lane & 15, kg = lane >> 4;
    const int i0 = blockIdx.x * 64;
    const int jb = blockIdx.y * 64;

    const unsigned short* arow[2];
    const unsigned short* brow[2];
    #pragma unroll
    for (int mi = 0; mi < 2; ++mi)
        arow[mi] = Ap + (size_t)(i0 + wr * 32 + mi * 16 + lr) * LDP + kg * 16;
    #pragma unroll
    for (int ni = 0; ni < 2; ++ni)
        brow[ni] = Bp + (size_t)(jb + wc * 32 + ni * 16 + lr) * LDP + kg * 16;

    f32x4 acc[2][2] = {};

    #pragma unroll
    for (int ks = 0; ks < K / 32; ++ks) {
        const int o = ks * 64;
        bf16x8 ah[2], al[2], bh[2], bl[2];
        #pragma unroll
        for (int mi = 0; mi < 2; ++mi) {
            ah[mi] = *(const bf16x8*)(arow[mi] + o);
            al[mi] = *(const bf16x8*)(arow[mi] + o + 8);
        }
        #pragma unroll
        for (int ni = 0; ni < 2; ++ni) {
            bh[ni] = *(const bf16x8*)(brow[ni] + o);
            bl[ni] = *(const bf16x8*)(brow[ni] + o + 8);
        }
        #pragma unroll
        for (int mi = 0; mi < 2; ++mi)
            #pragma unroll
            for (int ni = 0; ni < 2; ++ni) {
                acc[mi][ni] = __builtin_amdgcn_mfma_f32_16x16x32_bf16(
                    ah[mi], bh[ni], acc[mi][ni], 0, 0, 0);
                acc[mi][ni] = __builtin_amdgcn_mfma_f32_16x16x32_bf16(
                    ah[mi], bl[ni], acc[mi][ni], 0, 0, 0);
                acc[mi][ni] = __builtin_amdgcn_mfma_f32_16x16x32_bf16(
                    al[mi], bh[ni], acc[mi][ni], 0, 0, 0);
            }
    }

    // epilogue: C/D layout col=lane&15, row=(lane>>4)*4+reg (m89)
    #pragma unroll
    for (int ni = 0; ni < 2; ++ni) {
        const int col = jb + wc * 32 + ni * 16 + lr;
        const float bv = bias[col];
        if (MODE == 1) {
            float s = 0.f, sq = 0.f;
            #pragma unroll
            for (int mi = 0; mi < 2; ++mi)
                #pragma unroll
                for (int r = 0; r < 4; ++r) {
                    const int row = i0 + wr * 32 + mi * 16 + kg * 4 + r;
                    if (row < N_NODES) {
                        const float hv = acc[mi][ni][r] + bv;
                        outp[(size_t)row * NV + col] = hv;
                        s += hv; sq += hv * hv;
                    }
                }
            s  += __shfl_xor(s, 16);  s  += __shfl_xor(s, 32);
            sq += __shfl_xor(sq, 16); sq += __shfl_xor(sq, 32);
            if (kg == 0) {
                atomicAdd(&ssum[col], s);
                atomicAdd(&ssq[col], sq);
            }
        } else {
            #pragma unroll
            for (int mi = 0; mi < 2; ++mi)
                #pragma unroll
                for (int r = 0; r < 4; ++r) {
                    const int row = i0 + wr * 32 + mi * 16 + kg * 4 + r;
                    if (row < N_NODES)
                        outp[(size_t)row * NV + col] = acc[mi][ni][r] + bv;
                }
        }
    }
}

__global__ __launch_bounds__(256) void bnfinal_kernel(
    const float* __restrict__ ssum, const float* __restrict__ ssq,
    const float* __restrict__ gamma, const float* __restrict__ beta,
    float* __restrict__ aco, float* __restrict__ cco)
{
    const int j = threadIdx.x;
    const float inv_n = 1.0f / (float)N_NODES;
    const float mean = ssum[j] * inv_n;
    const float var  = ssq[j] * inv_n - mean * mean;
    const float rstd = rsqrtf(var + BN_EPS);
    const float a = rstd * gamma[j];
    aco[j] = a;
    cco[j] = beta[j] - mean * a;
}

extern "C" void kernel_launch(void* const* d_in, const int* in_sizes, int n_in,
                              void* d_out, int out_size, void* d_ws, size_t ws_size,
                              hipStream_t stream)
{
    const float* x     = (const float*)d_in[0];
    const int*   ei    = (const int*)d_in[1];      // int32 per harness contract
    const float* W1    = (const float*)d_in[2];
    const float* b1    = (const float*)d_in[3];
    const float* gamma = (const float*)d_in[4];
    const float* beta  = (const float*)d_in[5];
    const float* W2    = (const float*)d_in[6];
    const float* b2    = (const float*)d_in[7];
    float* out = (float*)d_out;

    // ws layout (~81 MB):
    // xp   [N*256 ushorts]  25.6 MB   (x+agg hi/lo planes)
    // h1   [N*256 floats]   51.2 MB   (fp32; reused in place as a2 planes)
    // w1t  [65536 ushorts]  128 KB    | w2t [65536 ushorts] 128 KB
    // ssum/ssq/aco/cco [256 each] | deg/off/cursor [N-ish] | esrc[E] | bsum[64]
    unsigned short* xp  = (unsigned short*)d_ws;
    float* h1           = (float*)(xp + (size_t)N_NODES * 256);
    unsigned short* a2p = (unsigned short*)h1;
    unsigned short* w1t = (unsigned short*)(h1 + (size_t)N_NODES * 256);
    unsigned short* w2t = w1t + 65536;
    float* ssum = (float*)(w2t + 65536);
    float* ssq  = ssum + D_HID;
    float* aco  = ssq  + D_HID;
    float* cco  = aco  + D_HID;
    int* deg    = (int*)(cco + D_HID);
    int* off    = deg + N_NODES;
    int* cursor = off + N_NODES + 1;
    int* esrc   = cursor + N_NODES;
    int* bsum   = esrc + N_EDGES;

    hipMemsetAsync(deg,  0, N_NODES * sizeof(int), stream);
    hipMemsetAsync(ssum, 0, 2 * D_HID * sizeof(float), stream);

    wsplit_kernel<<<dim3(2, 4), 256, 0, stream>>>(W1, w1t, D_IN, D_HID);
    wsplit_kernel<<<dim3(4, 2), 256, 0, stream>>>(W2, w2t, D_HID, D_OUT);

    deg_kernel<<<(N_EDGES + 255) / 256, 256, 0, stream>>>(ei, deg);
    scan1_kernel<<<NBLK_SCAN, 256, 0, stream>>>(deg, bsum);
    scan2_kernel<<<1, 64, 0, stream>>>(bsum, off);
    scan3_kernel<<<NBLK_SCAN, 256, 0, stream>>>(deg, bsum, off, cursor);
    fill_kernel<<<(N_EDGES + 255) / 256, 256, 0, stream>>>(ei, cursor, esrc);
    gather_kernel<<<(N_NODES * 64 + 255) / 256, 256, 0, stream>>>(x, off, esrc, xp);

    mlp_kernel<1><<<dim3(GX_MLP, D_HID / 64), 256, 0, stream>>>(
        xp, w1t, b1, h1, ssum, ssq);

    bnfinal_kernel<<<1, D_HID, 0, stream>>>(ssum, ssq, gamma, beta, aco, cco);

    bnrelu_split_kernel<<<(N_NODES * 32 + 255) / 256, 256, 0, stream>>>(
        h1, a2p, aco, cco);

    mlp_kernel<2><<<dim3(GX_MLP, D_OUT / 64), 256, 0, stream>>>(
        a2p, w2t, b2, out, nullptr, nullptr);
}

// Round 8
// 384.408 us; speedup vs baseline: 1.0881x; 1.0830x over previous
//
#include <hip/hip_runtime.h>

// GINConv pipeline. R8: R7's direct-global MFMA fragments were request-rate
// bound (64x16B loads at 512B stride = ~32 cache lines/instr; MfmaUtil 3.6%,
// VALUBusy 4.3%, HBM 14% — all idle). Fix: LDS staging as pure byte-moving
// (planes already pre-split, so staging has NO per-element VALU, unlike R5):
// coalesced contiguous 16B/lane global reads -> ds_write_b128 (XOR-swizzled)
// -> ds_read_b128 fragments (2-way conflicts only). Numerics unchanged.
//
// NOTE: harness delivers integer inputs as int32 — edge_index is const int*.

#define N_NODES 50000
#define N_EDGES 800000
#define D_IN    128
#define D_HID   256
#define D_OUT   128
#define BN_EPS  1e-5f

#define NBLK_SCAN 49   // ceil(50000 / 1024)
#define GX_MLP    782  // ceil(50000 / 64)

typedef __attribute__((ext_vector_type(8))) __bf16 bf16x8;
typedef __attribute__((ext_vector_type(4))) float  f32x4;
typedef __attribute__((ext_vector_type(8))) unsigned short us8;

__device__ __forceinline__ void split_bf16(float v, unsigned short& h, unsigned short& l)
{
    __bf16 bh = (__bf16)v;
    float  r  = v - (float)bh;
    __bf16 bl = (__bf16)r;
    h = __builtin_bit_cast(unsigned short, bh);
    l = __builtin_bit_cast(unsigned short, bl);
}

// ---------------- CSR build ----------------

__global__ __launch_bounds__(256) void deg_kernel(
    const int* __restrict__ ei, int* __restrict__ deg)
{
    const int e = blockIdx.x * 256 + threadIdx.x;
    if (e >= N_EDGES) return;
    atomicAdd(&deg[ei[N_EDGES + e]], 1);
}

__global__ __launch_bounds__(256) void scan1_kernel(
    const int* __restrict__ deg, int* __restrict__ bsum)
{
    __shared__ int ws[4];
    const int t = threadIdx.x;
    const int i0 = blockIdx.x * 1024 + t * 4;
    int s = 0;
    if (i0 + 3 < N_NODES) {
        const int4 d = *(const int4*)(deg + i0);
        s = d.x + d.y + d.z + d.w;
    } else {
        #pragma unroll
        for (int q = 0; q < 4; ++q) if (i0 + q < N_NODES) s += deg[i0 + q];
    }
    #pragma unroll
    for (int d = 32; d > 0; d >>= 1) s += __shfl_down(s, d);
    if ((t & 63) == 0) ws[t >> 6] = s;
    __syncthreads();
    if (t == 0) bsum[blockIdx.x] = ws[0] + ws[1] + ws[2] + ws[3];
}

__global__ __launch_bounds__(64) void scan2_kernel(
    int* __restrict__ bsum, int* __restrict__ off)
{
    const int lane = threadIdx.x;
    const int v = (lane < NBLK_SCAN) ? bsum[lane] : 0;
    int incl = v;
    #pragma unroll
    for (int d = 1; d < 64; d <<= 1) {
        const int up = __shfl_up(incl, d);
        if (lane >= d) incl += up;
    }
    if (lane < NBLK_SCAN) bsum[lane] = incl - v;
    if (lane == 0) off[N_NODES] = N_EDGES;
}

__global__ __launch_bounds__(256) void scan3_kernel(
    const int* __restrict__ deg, const int* __restrict__ bsum,
    int* __restrict__ off, int* __restrict__ cursor)
{
    __shared__ int ws[4];
    const int t = threadIdx.x;
    const int lane = t & 63, wid = t >> 6;
    const int i0 = blockIdx.x * 1024 + t * 4;
    int4 d = make_int4(0, 0, 0, 0);
    if (i0 + 3 < N_NODES) {
        d = *(const int4*)(deg + i0);
    } else {
        if (i0 + 0 < N_NODES) d.x = deg[i0 + 0];
        if (i0 + 1 < N_NODES) d.y = deg[i0 + 1];
        if (i0 + 2 < N_NODES) d.z = deg[i0 + 2];
    }
    const int tsum = d.x + d.y + d.z + d.w;
    int incl = tsum;
    #pragma unroll
    for (int dd = 1; dd < 64; dd <<= 1) {
        const int up = __shfl_up(incl, dd);
        if (lane >= dd) incl += up;
    }
    if (lane == 63) ws[wid] = incl;
    __syncthreads();
    int wbase = 0;
    for (int w = 0; w < wid; ++w) wbase += ws[w];
    const int e = bsum[blockIdx.x] + wbase + incl - tsum;
    int4 o;
    o.x = e; o.y = e + d.x; o.z = o.y + d.y; o.w = o.z + d.z;
    if (i0 + 3 < N_NODES) {
        *(int4*)(off + i0)    = o;
        *(int4*)(cursor + i0) = o;
    } else {
        if (i0 + 0 < N_NODES) { off[i0 + 0] = o.x; cursor[i0 + 0] = o.x; }
        if (i0 + 1 < N_NODES) { off[i0 + 1] = o.y; cursor[i0 + 1] = o.y; }
        if (i0 + 2 < N_NODES) { off[i0 + 2] = o.z; cursor[i0 + 2] = o.z; }
    }
}

__global__ __launch_bounds__(256) void fill_kernel(
    const int* __restrict__ ei, int* __restrict__ cursor, int* __restrict__ esrc)
{
    const int e = blockIdx.x * 256 + threadIdx.x;
    if (e >= N_EDGES) return;
    const int pos = atomicAdd(&cursor[ei[N_EDGES + e]], 1);
    esrc[pos] = ei[e];
}

// ---------------- gather + self + bf16 split (fused) ----------------
// xp layout: [row][k/8][hi8|lo8] ushorts, row stride 256.

__global__ __launch_bounds__(256) void gather_kernel(
    const float* __restrict__ x, const int* __restrict__ off,
    const int* __restrict__ esrc, unsigned short* __restrict__ xp)
{
    const int gtid = blockIdx.x * 256 + threadIdx.x;
    const int node = gtid >> 6;
    const int lane = gtid & 63;
    if (node >= N_NODES) return;
    const int e0 = off[node], e1 = off[node + 1];
    const float2 xv = ((const float2*)(x + (size_t)node * D_IN))[lane];
    float2 acc = xv;                               // (1+eps)*x with eps=0
    for (int e = e0; e < e1; e += 64) {
        const int n = min(64, e1 - e);
        const int myS = (lane < n) ? esrc[e + lane] : 0;
        for (int j = 0; j < n; ++j) {
            const int s = __shfl(myS, j);
            const float2 v = ((const float2*)(x + (size_t)s * D_IN))[lane];
            acc.x += v.x;
            acc.y += v.y;
        }
    }
    unsigned short h0, l0, h1_, l1_;
    split_bf16(acc.x, h0, l0);
    split_bf16(acc.y, h1_, l1_);
    // channels 2*lane, 2*lane+1 -> block b = lane>>2, pos = (2*lane)&7
    const int o = node * 256 + (lane >> 2) * 16 + ((2 * lane) & 7);
    *(ushort2*)&xp[o]     = make_ushort2(h0, h1_);
    *(ushort2*)&xp[o + 8] = make_ushort2(l0, l1_);
}

// ---------------- W transpose + split ----------------
// src [K][N] f32 -> dst [n][k/8][hi8|lo8] ushorts (row stride 2K).

__global__ __launch_bounds__(256) void wsplit_kernel(
    const float* __restrict__ src, unsigned short* __restrict__ dst,
    int K, int N)
{
    __shared__ float tile[64][65];
    const int k0 = blockIdx.x * 64, n0 = blockIdx.y * 64;
    const int t = threadIdx.x;
    const int tr = t >> 4, tc4 = (t & 15) * 4;
    #pragma unroll
    for (int i = 0; i < 4; ++i) {
        const int r = tr + i * 16;
        *(float4*)&tile[r][tc4] = *(const float4*)(src + (size_t)(k0 + r) * N + n0 + tc4);
    }
    __syncthreads();
    #pragma unroll
    for (int i = 0; i < 4; ++i) {
        const int n = tr + i * 16;
        ushort4 hh, ll;
        split_bf16(tile[tc4 + 0][n], hh.x, ll.x);
        split_bf16(tile[tc4 + 1][n], hh.y, ll.y);
        split_bf16(tile[tc4 + 2][n], hh.z, ll.z);
        split_bf16(tile[tc4 + 3][n], hh.w, ll.w);
        const int kk = k0 + tc4;                 // multiple of 4
        const int o = (n0 + n) * 2 * K + ((kk >> 3) << 4) + (kk & 7);
        *(ushort4*)&dst[o]     = hh;
        *(ushort4*)&dst[o + 8] = ll;
    }
}

// ---------------- BN + ReLU + split, in place over h1 ----------------
// Each thread reads and rewrites exactly its own 32-byte span (race-free).

__global__ __launch_bounds__(256) void bnrelu_split_kernel(
    const float* h1_in, unsigned short* a2_out,
    const float* __restrict__ aco, const float* __restrict__ cco)
{
    const int t = blockIdx.x * 256 + threadIdx.x;
    if (t >= N_NODES * 32) return;
    const int row = t >> 5, cb = t & 31;         // block of 8 channels
    const float* p = h1_in + (size_t)row * 256 + cb * 8;
    const float4 v0 = *(const float4*)p;
    const float4 v1 = *(const float4*)(p + 4);
    const float4 a0 = *(const float4*)(aco + cb * 8);
    const float4 a1 = *(const float4*)(aco + cb * 8 + 4);
    const float4 c0 = *(const float4*)(cco + cb * 8);
    const float4 c1 = *(const float4*)(cco + cb * 8 + 4);
    float r[8];
    r[0] = fmaxf(fmaf(v0.x, a0.x, c0.x), 0.f);
    r[1] = fmaxf(fmaf(v0.y, a0.y, c0.y), 0.f);
    r[2] = fmaxf(fmaf(v0.z, a0.z, c0.z), 0.f);
    r[3] = fmaxf(fmaf(v0.w, a0.w, c0.w), 0.f);
    r[4] = fmaxf(fmaf(v1.x, a1.x, c1.x), 0.f);
    r[5] = fmaxf(fmaf(v1.y, a1.y, c1.y), 0.f);
    r[6] = fmaxf(fmaf(v1.z, a1.z, c1.z), 0.f);
    r[7] = fmaxf(fmaf(v1.w, a1.w, c1.w), 0.f);
    us8 hi, lo;
    #pragma unroll
    for (int q = 0; q < 8; ++q) {
        unsigned short h, l;
        split_bf16(r[q], h, l);
        hi[q] = h; lo[q] = l;
    }
    unsigned short* d = a2_out + (size_t)row * 512 + cb * 16;
    *(us8*)d       = hi;
    *(us8*)(d + 8) = lo;
}

// ---------------- MFMA GEMMs, LDS-staged (pure byte-move) ----------------
// MODE 1: h1 = (x+agg) @ W1 + b1 (+ BN col stats)   A=xp  B=w1t  K=128 N=256
// MODE 2: out = a2 @ W2 + b2                        A=a2p B=w2t  K=256 N=128
// Block: 4 waves 2x2, tile 64x64; wave 32x32 = 2x2 mfma_f32_16x16x32_bf16.
// Per 128-k chunk: stage A-tile 64x512B + B-tile 64x512B into LDS with
// coalesced b128 global reads; LDS byte addr XOR-swizzled by (row&7)<<4 on
// BOTH write and read so stride-512B fragment ds_read_b128 is 2-way (free).
// Triple MFMA hi/lo, lo*lo dropped. OOB A-rows read garbage inside d_ws;
// masked at store (and excluded from BN stats).

template<int MODE>
__global__ __launch_bounds__(256) void mlp_kernel(
    const unsigned short* __restrict__ Ap, const unsigned short* __restrict__ Bp,
    const float* __restrict__ bias, float* __restrict__ outp,
    float* __restrict__ ssum, float* __restrict__ ssq)
{
    constexpr int K    = (MODE == 1) ? 128 : 256;
    constexpr int NV   = (MODE == 1) ? 256 : 128;
    constexpr int ROWB = 4 * K;            // bytes per plane row (hi+lo)
    constexpr int NCH  = K / 128;          // 128-k chunks

    __shared__ __attribute__((aligned(16))) unsigned char lA[32768];
    __shared__ __attribute__((aligned(16))) unsigned char lB[32768];

    const int tid  = threadIdx.x;
    const int lane = tid & 63;
    const int w    = tid >> 6;
    const int wr   = w >> 1, wc = w & 1;
    const int lr   = lane & 15, kg = lane >> 4;
    const int i0   = blockIdx.x * 64;
    const int jb   = blockIdx.y * 64;

    const unsigned char* Ag = (const unsigned char*)Ap;
    const unsigned char* Bg = (const unsigned char*)Bp;

    f32x4 acc[2][2] = {};

    for (int ch = 0; ch < NCH; ++ch) {
        if (ch) __syncthreads();
        // ---- stage 64 KB: coalesced contiguous reads, swizzled LDS writes ----
        #pragma unroll
        for (int it = 0; it < 8; ++it) {
            const int o   = it * 4096 + tid * 16;
            const int row = o >> 9;
            const int col = o & 511;
            const int d   = o ^ ((row & 7) << 4);
            const float4 va = *(const float4*)(Ag + (size_t)(i0 + row) * ROWB + ch * 512 + col);
            *(float4*)&lA[d] = va;
            const float4 vb = *(const float4*)(Bg + (size_t)(jb + row) * ROWB + ch * 512 + col);
            *(float4*)&lB[d] = vb;
        }
        __syncthreads();

        // ---- 4 k-steps of 32 from LDS ----
        #pragma unroll
        for (int ks = 0; ks < 4; ++ks) {
            bf16x8 ah[2], al[2], bh[2], bl[2];
            #pragma unroll
            for (int mi = 0; mi < 2; ++mi) {
                const int ar = wr * 32 + mi * 16 + lr;
                const int s  = (ar & 7) << 4;
                const int o1 = ar * 512 + ks * 128 + kg * 32;
                ah[mi] = *(const bf16x8*)&lA[o1 ^ s];
                al[mi] = *(const bf16x8*)&lA[(o1 + 16) ^ s];
            }
            #pragma unroll
            for (int ni = 0; ni < 2; ++ni) {
                const int br = wc * 32 + ni * 16 + lr;
                const int s  = (br & 7) << 4;
                const int o2 = br * 512 + ks * 128 + kg * 32;
                bh[ni] = *(const bf16x8*)&lB[o2 ^ s];
                bl[ni] = *(const bf16x8*)&lB[(o2 + 16) ^ s];
            }
            #pragma unroll
            for (int mi = 0; mi < 2; ++mi)
                #pragma unroll
                for (int ni = 0; ni < 2; ++ni) {
                    acc[mi][ni] = __builtin_amdgcn_mfma_f32_16x16x32_bf16(
                        ah[mi], bh[ni], acc[mi][ni], 0, 0, 0);
                    acc[mi][ni] = __builtin_amdgcn_mfma_f32_16x16x32_bf16(
                        ah[mi], bl[ni], acc[mi][ni], 0, 0, 0);
                    acc[mi][ni] = __builtin_amdgcn_mfma_f32_16x16x32_bf16(
                        al[mi], bh[ni], acc[mi][ni], 0, 0, 0);
                }
        }
    }

    // ---- epilogue: C/D layout col=lane&15, row=(lane>>4)*4+reg (m89) ----
    #pragma unroll
    for (int ni = 0; ni < 2; ++ni) {
        const int col = jb + wc * 32 + ni * 16 + lr;
        const float bv = bias[col];
        if (MODE == 1) {
            float s = 0.f, sq = 0.f;
            #pragma unroll
            for (int mi = 0; mi < 2; ++mi)
                #pragma unroll
                for (int r = 0; r < 4; ++r) {
                    const int row = i0 + wr * 32 + mi * 16 + kg * 4 + r;
                    if (row < N_NODES) {
                        const float hv = acc[mi][ni][r] + bv;
                        outp[(size_t)row * NV + col] = hv;
                        s += hv; sq += hv * hv;
                    }
                }
            s  += __shfl_xor(s, 16);  s  += __shfl_xor(s, 32);
            sq += __shfl_xor(sq, 16); sq += __shfl_xor(sq, 32);
            if (kg == 0) {
                atomicAdd(&ssum[col], s);
                atomicAdd(&ssq[col], sq);
            }
        } else {
            #pragma unroll
            for (int mi = 0; mi < 2; ++mi)
                #pragma unroll
                for (int r = 0; r < 4; ++r) {
                    const int row = i0 + wr * 32 + mi * 16 + kg * 4 + r;
                    if (row < N_NODES)
                        outp[(size_t)row * NV + col] = acc[mi][ni][r] + bv;
                }
        }
    }
}

__global__ __launch_bounds__(256) void bnfinal_kernel(
    const float* __restrict__ ssum, const float* __restrict__ ssq,
    const float* __restrict__ gamma, const float* __restrict__ beta,
    float* __restrict__ aco, float* __restrict__ cco)
{
    const int j = threadIdx.x;
    const float inv_n = 1.0f / (float)N_NODES;
    const float mean = ssum[j] * inv_n;
    const float var  = ssq[j] * inv_n - mean * mean;
    const float rstd = rsqrtf(var + BN_EPS);
    const float a = rstd * gamma[j];
    aco[j] = a;
    cco[j] = beta[j] - mean * a;
}

extern "C" void kernel_launch(void* const* d_in, const int* in_sizes, int n_in,
                              void* d_out, int out_size, void* d_ws, size_t ws_size,
                              hipStream_t stream)
{
    const float* x     = (const float*)d_in[0];
    const int*   ei    = (const int*)d_in[1];      // int32 per harness contract
    const float* W1    = (const float*)d_in[2];
    const float* b1    = (const float*)d_in[3];
    const float* gamma = (const float*)d_in[4];
    const float* beta  = (const float*)d_in[5];
    const float* W2    = (const float*)d_in[6];
    const float* b2    = (const float*)d_in[7];
    float* out = (float*)d_out;

    // ws layout (~84 MB):
    // xp   [N*256 ushorts]  25.6 MB   (x+agg hi/lo planes)
    // h1   [N*256 floats]   51.2 MB   (fp32; reused in place as a2 planes)
    // w1t  [65536 ushorts]  128 KB    | w2t [65536 ushorts] 128 KB
    // ssum/ssq/aco/cco | deg/off/cursor | esrc[E] | bsum[64]
    unsigned short* xp  = (unsigned short*)d_ws;
    float* h1           = (float*)(xp + (size_t)N_NODES * 256);
    unsigned short* a2p = (unsigned short*)h1;
    unsigned short* w1t = (unsigned short*)(h1 + (size_t)N_NODES * 256);
    unsigned short* w2t = w1t + 65536;
    float* ssum = (float*)(w2t + 65536);
    float* ssq  = ssum + D_HID;
    float* aco  = ssq  + D_HID;
    float* cco  = aco  + D_HID;
    int* deg    = (int*)(cco + D_HID);
    int* off    = deg + N_NODES;
    int* cursor = off + N_NODES + 1;
    int* esrc   = cursor + N_NODES;
    int* bsum   = esrc + N_EDGES;

    hipMemsetAsync(deg,  0, N_NODES * sizeof(int), stream);
    hipMemsetAsync(ssum, 0, 2 * D_HID * sizeof(float), stream);

    wsplit_kernel<<<dim3(2, 4), 256, 0, stream>>>(W1, w1t, D_IN, D_HID);
    wsplit_kernel<<<dim3(4, 2), 256, 0, stream>>>(W2, w2t, D_HID, D_OUT);

    deg_kernel<<<(N_EDGES + 255) / 256, 256, 0, stream>>>(ei, deg);
    scan1_kernel<<<NBLK_SCAN, 256, 0, stream>>>(deg, bsum);
    scan2_kernel<<<1, 64, 0, stream>>>(bsum, off);
    scan3_kernel<<<NBLK_SCAN, 256, 0, stream>>>(deg, bsum, off, cursor);
    fill_kernel<<<(N_EDGES + 255) / 256, 256, 0, stream>>>(ei, cursor, esrc);
    gather_kernel<<<(N_NODES * 64 + 255) / 256, 256, 0, stream>>>(x, off, esrc, xp);

    mlp_kernel<1><<<dim3(GX_MLP, D_HID / 64), 256, 0, stream>>>(
        xp, w1t, b1, h1, ssum, ssq);

    bnfinal_kernel<<<1, D_HID, 0, stream>>>(ssum, ssq, gamma, beta, aco, cco);

    bnrelu_split_kernel<<<(N_NODES * 32 + 255) / 256, 256, 0, stream>>>(
        h1, a2p, aco, cco);

    mlp_kernel<2><<<dim3(GX_MLP, D_OUT / 64), 256, 0, stream>>>(
        a2p, w2t, b2, out, nullptr, nullptr);
}